// Round 1
// baseline (1046.611 us; speedup 1.0000x reference)
//
#include <hip/hip_runtime.h>

#define NEG_SLOPE 0.2f

__device__ __forceinline__ float eluf(float x) { return x > 0.f ? x : __expf(x) - 1.f; }
__device__ __forceinline__ float lrelu(float x) { return x > 0.f ? x : NEG_SLOPE * x; }

// ---------------- CSR build (dst-sorted adjacency, self-loops appended) ----------------
__global__ void count_kernel(const int* __restrict__ ei, int E, int N, int* __restrict__ counts) {
    int i = blockIdx.x * blockDim.x + threadIdx.x;
    int Et = E + N;
    if (i >= Et) return;
    int d = (i < E) ? ei[E + i] : (i - E);
    atomicAdd(&counts[d], 1);
}

// single-block inclusive scan -> row_ptr; also rewrites counts buffer into exclusive prefix (cursor)
__global__ void scan_kernel(int* __restrict__ counts_cursor, int* __restrict__ row_ptr, int N) {
    __shared__ int sdata[1024];
    __shared__ int s_carry;
    int t = threadIdx.x;
    if (t == 0) { s_carry = 0; row_ptr[0] = 0; }
    __syncthreads();
    for (int start = 0; start < N; start += 1024) {
        int i = start + t;
        int v = (i < N) ? counts_cursor[i] : 0;
        sdata[t] = v;
        __syncthreads();
        for (int d = 1; d < 1024; d <<= 1) {
            int add = (t >= d) ? sdata[t - d] : 0;
            __syncthreads();
            sdata[t] += add;
            __syncthreads();
        }
        int incl = sdata[t] + s_carry;
        if (i < N) { row_ptr[i + 1] = incl; counts_cursor[i] = incl - v; }
        __syncthreads();
        if (t == 1023) s_carry = incl;
        __syncthreads();
    }
}

__global__ void fill_kernel(const int* __restrict__ ei, int E, int N,
                            int* __restrict__ cursor, int* __restrict__ col) {
    int i = blockIdx.x * blockDim.x + threadIdx.x;
    int Et = E + N;
    if (i >= Et) return;
    int s, d;
    if (i < E) { s = ei[i]; d = ei[E + i]; } else { s = d = i - E; }
    int pos = atomicAdd(&cursor[d], 1);
    col[pos] = s;
}

// ---------------- fp32 tiled GEMM: C[M,N] = A[M,K] @ B[K,N] ----------------
// 64x64 tile, BK=16, 256 threads, 4x4 per thread. M may be ragged; N,K multiples of 64/16.
__global__ __launch_bounds__(256) void sgemm64(const float* __restrict__ A, const float* __restrict__ B,
                                               float* __restrict__ C, int M, int N, int K) {
    __shared__ float As[16][68];
    __shared__ float Bs[16][64];
    int t = threadIdx.x;
    int tx = t & 15, ty = t >> 4;
    int row0 = blockIdx.y * 64, col0 = blockIdx.x * 64;
    float c[4][4] = {};
    for (int kt = 0; kt < K; kt += 16) {
        // A: thread t loads (m = t>>4 + 16p, k = t&15)
        #pragma unroll
        for (int p = 0; p < 4; p++) {
            int m = (t >> 4) + p * 16;
            int k = t & 15;
            int gr = row0 + m;
            As[k][m] = (gr < M) ? A[(size_t)gr * K + kt + k] : 0.f;
        }
        // B: thread t loads (n = t&63, k = t>>6 + 4p)
        #pragma unroll
        for (int p = 0; p < 4; p++) {
            int n = t & 63;
            int k = (t >> 6) + p * 4;
            Bs[k][n] = B[(size_t)(kt + k) * N + col0 + n];
        }
        __syncthreads();
        #pragma unroll
        for (int k = 0; k < 16; k++) {
            float4 av = *(const float4*)&As[k][ty * 4];
            float4 bv = *(const float4*)&Bs[k][tx * 4];
            c[0][0] += av.x * bv.x; c[0][1] += av.x * bv.y; c[0][2] += av.x * bv.z; c[0][3] += av.x * bv.w;
            c[1][0] += av.y * bv.x; c[1][1] += av.y * bv.y; c[1][2] += av.y * bv.z; c[1][3] += av.y * bv.w;
            c[2][0] += av.z * bv.x; c[2][1] += av.z * bv.y; c[2][2] += av.z * bv.z; c[2][3] += av.z * bv.w;
            c[3][0] += av.w * bv.x; c[3][1] += av.w * bv.y; c[3][2] += av.w * bv.z; c[3][3] += av.w * bv.w;
        }
        __syncthreads();
    }
    #pragma unroll
    for (int i = 0; i < 4; i++) {
        int gr = row0 + ty * 4 + i;
        if (gr < M) {
            float4 v = make_float4(c[i][0], c[i][1], c[i][2], c[i][3]);
            *(float4*)&C[(size_t)gr * N + col0 + tx * 4] = v;
        }
    }
}

// ---------------- per-node attention logits, layer 1 (H=4, C=256) ----------------
__global__ void s1_kernel(const float* __restrict__ h1, const float* __restrict__ a_src,
                          const float* __restrict__ a_dst, float* __restrict__ ssrc,
                          float* __restrict__ sdst, int N) {
    int wid = (blockIdx.x * blockDim.x + threadIdx.x) >> 6;
    int lane = threadIdx.x & 63;
    if (wid >= N) return;
    const float* row = h1 + (size_t)wid * 1024;
    float aS[4] = {0, 0, 0, 0}, aD[4] = {0, 0, 0, 0};
    #pragma unroll
    for (int k = 0; k < 16; k++) {
        int c = k * 64 + lane;
        float v = row[c];
        int h = k >> 2;
        aS[h] += v * a_src[c];
        aD[h] += v * a_dst[c];
    }
    #pragma unroll
    for (int h = 0; h < 4; h++) {
        float s = aS[h], d = aD[h];
        for (int off = 32; off; off >>= 1) { s += __shfl_xor(s, off); d += __shfl_xor(d, off); }
        if (lane == 0) { ssrc[wid * 4 + h] = s; sdst[wid * 4 + h] = d; }
    }
}

// ---------------- per-node attention logits, layer 2 (H=1, C=256) ----------------
__global__ void s2_kernel(const float* __restrict__ h2, const float* __restrict__ a_src,
                          const float* __restrict__ a_dst, float* __restrict__ ssrc,
                          float* __restrict__ sdst, int N) {
    int wid = (blockIdx.x * blockDim.x + threadIdx.x) >> 6;
    int lane = threadIdx.x & 63;
    if (wid >= N) return;
    const float4* row = (const float4*)(h2 + (size_t)wid * 256);
    const float4* as4 = (const float4*)a_src;
    const float4* ad4 = (const float4*)a_dst;
    float4 v = row[lane], a = as4[lane], d = ad4[lane];
    float s = v.x * a.x + v.y * a.y + v.z * a.z + v.w * a.w;
    float t = v.x * d.x + v.y * d.y + v.z * d.z + v.w * d.w;
    for (int off = 32; off; off >>= 1) { s += __shfl_xor(s, off); t += __shfl_xor(t, off); }
    if (lane == 0) { ssrc[wid] = s; sdst[wid] = t; }
}

// ---------------- layer-1 aggregation: one wave per dst node (H=4, C=256) ----------------
// out[n] = elu( (sum_e exp(e)-weighted h1[src]) / denom + b1 )
__global__ __launch_bounds__(256) void agg1_kernel(const float* __restrict__ h1,
        const float* __restrict__ ssrc, const float* __restrict__ sdst,
        const int* __restrict__ row_ptr, const int* __restrict__ col,
        const float* __restrict__ bias, float* __restrict__ out, int N) {
    int wid = (blockIdx.x * blockDim.x + threadIdx.x) >> 6;
    int lane = threadIdx.x & 63;
    if (wid >= N) return;
    int base = row_ptr[wid];
    int deg = row_ptr[wid + 1] - base;
    float sd0 = sdst[wid * 4 + 0], sd1 = sdst[wid * 4 + 1];
    float sd2 = sdst[wid * 4 + 2], sd3 = sdst[wid * 4 + 3];
    // pass 1: per-head max over incoming edges (lane-parallel, then wave allreduce)
    float m0 = -1e30f, m1 = -1e30f, m2 = -1e30f, m3 = -1e30f;
    for (int i = lane; i < deg; i += 64) {
        int s = col[base + i];
        const float* sp = ssrc + s * 4;
        m0 = fmaxf(m0, lrelu(sp[0] + sd0));
        m1 = fmaxf(m1, lrelu(sp[1] + sd1));
        m2 = fmaxf(m2, lrelu(sp[2] + sd2));
        m3 = fmaxf(m3, lrelu(sp[3] + sd3));
    }
    #pragma unroll
    for (int off = 32; off; off >>= 1) {
        m0 = fmaxf(m0, __shfl_xor(m0, off));
        m1 = fmaxf(m1, __shfl_xor(m1, off));
        m2 = fmaxf(m2, __shfl_xor(m2, off));
        m3 = fmaxf(m3, __shfl_xor(m3, off));
    }
    // pass 2: serial edge loop; lanes split the 1024 channels (float4 per head)
    float4 a0 = {0,0,0,0}, a1 = {0,0,0,0}, a2 = {0,0,0,0}, a3 = {0,0,0,0};
    float d0 = 0.f, d1 = 0.f, d2 = 0.f, d3 = 0.f;
    for (int i = 0; i < deg; i++) {
        int s = col[base + i];
        const float* sp = ssrc + s * 4;
        float x0 = __expf(lrelu(sp[0] + sd0) - m0); d0 += x0;
        float x1 = __expf(lrelu(sp[1] + sd1) - m1); d1 += x1;
        float x2 = __expf(lrelu(sp[2] + sd2) - m2); d2 += x2;
        float x3 = __expf(lrelu(sp[3] + sd3) - m3); d3 += x3;
        const float4* row = (const float4*)(h1 + (size_t)s * 1024);
        float4 v;
        v = row[lane];       a0.x += x0 * v.x; a0.y += x0 * v.y; a0.z += x0 * v.z; a0.w += x0 * v.w;
        v = row[64 + lane];  a1.x += x1 * v.x; a1.y += x1 * v.y; a1.z += x1 * v.z; a1.w += x1 * v.w;
        v = row[128 + lane]; a2.x += x2 * v.x; a2.y += x2 * v.y; a2.z += x2 * v.z; a2.w += x2 * v.w;
        v = row[192 + lane]; a3.x += x3 * v.x; a3.y += x3 * v.y; a3.z += x3 * v.z; a3.w += x3 * v.w;
    }
    float i0 = 1.f / (d0 + 1e-16f), i1 = 1.f / (d1 + 1e-16f);
    float i2 = 1.f / (d2 + 1e-16f), i3 = 1.f / (d3 + 1e-16f);
    size_t ob = (size_t)wid * 1024;
    int c = lane * 4;
    float4 o;
    o.x = eluf(a0.x * i0 + bias[c + 0]); o.y = eluf(a0.y * i0 + bias[c + 1]);
    o.z = eluf(a0.z * i0 + bias[c + 2]); o.w = eluf(a0.w * i0 + bias[c + 3]);
    *(float4*)(out + ob + c) = o;
    o.x = eluf(a1.x * i1 + bias[256 + c + 0]); o.y = eluf(a1.y * i1 + bias[256 + c + 1]);
    o.z = eluf(a1.z * i1 + bias[256 + c + 2]); o.w = eluf(a1.w * i1 + bias[256 + c + 3]);
    *(float4*)(out + ob + 256 + c) = o;
    o.x = eluf(a2.x * i2 + bias[512 + c + 0]); o.y = eluf(a2.y * i2 + bias[512 + c + 1]);
    o.z = eluf(a2.z * i2 + bias[512 + c + 2]); o.w = eluf(a2.w * i2 + bias[512 + c + 3]);
    *(float4*)(out + ob + 512 + c) = o;
    o.x = eluf(a3.x * i3 + bias[768 + c + 0]); o.y = eluf(a3.y * i3 + bias[768 + c + 1]);
    o.z = eluf(a3.z * i3 + bias[768 + c + 2]); o.w = eluf(a3.w * i3 + bias[768 + c + 3]);
    *(float4*)(out + ob + 768 + c) = o;
}

// ---------------- layer-2 aggregation: one wave per dst node (H=1, C=256) ----------------
__global__ __launch_bounds__(256) void agg2_kernel(const float* __restrict__ h2,
        const float* __restrict__ ssrc, const float* __restrict__ sdst,
        const int* __restrict__ row_ptr, const int* __restrict__ col,
        const float* __restrict__ bias, float* __restrict__ out, int N) {
    int wid = (blockIdx.x * blockDim.x + threadIdx.x) >> 6;
    int lane = threadIdx.x & 63;
    if (wid >= N) return;
    int base = row_ptr[wid];
    int deg = row_ptr[wid + 1] - base;
    float sd = sdst[wid];
    float m = -1e30f;
    for (int i = lane; i < deg; i += 64) {
        int s = col[base + i];
        m = fmaxf(m, lrelu(ssrc[s] + sd));
    }
    #pragma unroll
    for (int off = 32; off; off >>= 1) m = fmaxf(m, __shfl_xor(m, off));
    float4 a = {0,0,0,0};
    float den = 0.f;
    for (int i = 0; i < deg; i++) {
        int s = col[base + i];
        float x = __expf(lrelu(ssrc[s] + sd) - m); den += x;
        float4 v = ((const float4*)(h2 + (size_t)s * 256))[lane];
        a.x += x * v.x; a.y += x * v.y; a.z += x * v.z; a.w += x * v.w;
    }
    float inv = 1.f / (den + 1e-16f);
    int c = lane * 4;
    float4 o;
    o.x = eluf(a.x * inv + bias[c + 0]);
    o.y = eluf(a.y * inv + bias[c + 1]);
    o.z = eluf(a.z * inv + bias[c + 2]);
    o.w = eluf(a.w * inv + bias[c + 3]);
    *(float4*)(out + (size_t)wid * 256 + c) = o;
}

// ---------------- mean over nodes -> graph_features [256] ----------------
__global__ void mean_kernel(const float* __restrict__ h, float* __restrict__ gf, int N) {
    int c = threadIdx.x;
    int per = (N + gridDim.x - 1) / gridDim.x;
    int n0 = blockIdx.x * per;
    int n1 = min(N, n0 + per);
    float acc = 0.f;
    for (int n = n0; n < n1; n++) acc += h[(size_t)n * 256 + c];
    atomicAdd(&gf[c], acc * (1.0f / N));
}

// ---------------- influence head: sigmoid(relu(h@Wp1+bp1)@Wp2+bp2), 4 nodes/block ----------------
__global__ __launch_bounds__(128) void infl_kernel(const float* __restrict__ h,
        const float* __restrict__ Wp1, const float* __restrict__ bp1,
        const float* __restrict__ Wp2, const float* __restrict__ bp2,
        float* __restrict__ infl, int N) {
    __shared__ float sh[4][256];
    __shared__ float red[4][128];
    int nb = blockIdx.x * 4;
    int t = threadIdx.x;
    #pragma unroll
    for (int r = 0; r < 4; r++) {
        int n = nb + r;
        if (n < N) {
            sh[r][t] = h[(size_t)n * 256 + t];
            sh[r][t + 128] = h[(size_t)n * 256 + t + 128];
        }
    }
    __syncthreads();
    float acc0 = bp1[t], acc1 = acc0, acc2 = acc0, acc3 = acc0;
    for (int k = 0; k < 256; k++) {
        float w = Wp1[k * 128 + t];
        acc0 += sh[0][k] * w;
        acc1 += sh[1][k] * w;
        acc2 += sh[2][k] * w;
        acc3 += sh[3][k] * w;
    }
    float w2 = Wp2[t];
    red[0][t] = fmaxf(acc0, 0.f) * w2;
    red[1][t] = fmaxf(acc1, 0.f) * w2;
    red[2][t] = fmaxf(acc2, 0.f) * w2;
    red[3][t] = fmaxf(acc3, 0.f) * w2;
    __syncthreads();
    for (int s = 64; s > 0; s >>= 1) {
        if (t < s) {
            red[0][t] += red[0][t + s];
            red[1][t] += red[1][t + s];
            red[2][t] += red[2][t + s];
            red[3][t] += red[3][t + s];
        }
        __syncthreads();
    }
    if (t < 4) {
        int n = nb + t;
        if (n < N) {
            float v = red[t][0] + bp2[0];
            infl[n] = 1.f / (1.f + __expf(-v));
        }
    }
}

extern "C" void kernel_launch(void* const* d_in, const int* in_sizes, int n_in,
                              void* d_out, int out_size, void* d_ws, size_t ws_size,
                              hipStream_t stream) {
    const float* x   = (const float*)d_in[0];
    const int*   ei  = (const int*)d_in[1];
    const float* W1  = (const float*)d_in[2];
    const float* as1 = (const float*)d_in[3];
    const float* ad1 = (const float*)d_in[4];
    const float* b1  = (const float*)d_in[5];
    const float* W2  = (const float*)d_in[6];
    const float* as2 = (const float*)d_in[7];
    const float* ad2 = (const float*)d_in[8];
    const float* b2  = (const float*)d_in[9];
    const float* Wp1 = (const float*)d_in[10];
    const float* bp1 = (const float*)d_in[11];
    const float* Wp2 = (const float*)d_in[12];
    const float* bp2 = (const float*)d_in[13];

    const int N  = in_sizes[0] / 384;   // 20000
    const int E  = in_sizes[1] / 2;     // 320000
    const int Et = E + N;               // with self loops

    // workspace layout (fp32 / int32)
    float* ws  = (float*)d_ws;
    float* h1  = ws;  ws += (size_t)N * 1024;   // x@W1
    float* h1e = ws;  ws += (size_t)N * 1024;   // elu(gat1)
    float* h2  = ws;  ws += (size_t)N * 256;    // h1e@W2
    float* ss1 = ws;  ws += (size_t)N * 4;
    float* sd1 = ws;  ws += (size_t)N * 4;
    float* ss2 = ws;  ws += (size_t)N;
    float* sd2 = ws;  ws += (size_t)N;
    int* row_ptr = (int*)ws;
    int* cursor  = row_ptr + (N + 1);
    int* col     = cursor + N;          // Et entries

    float* out_h  = (float*)d_out;            // [N,256]
    float* out_gf = out_h + (size_t)N * 256;  // [256]
    float* out_if = out_gf + 256;             // [N]

    // CSR build
    hipMemsetAsync(cursor, 0, (size_t)N * sizeof(int), stream);
    count_kernel<<<(Et + 255) / 256, 256, 0, stream>>>(ei, E, N, cursor);
    scan_kernel<<<1, 1024, 0, stream>>>(cursor, row_ptr, N);
    fill_kernel<<<(Et + 255) / 256, 256, 0, stream>>>(ei, E, N, cursor, col);

    // layer 1
    dim3 g1(1024 / 64, (N + 63) / 64);
    sgemm64<<<g1, 256, 0, stream>>>(x, W1, h1, N, 1024, 384);
    s1_kernel<<<(N + 3) / 4, 256, 0, stream>>>(h1, as1, ad1, ss1, sd1, N);
    agg1_kernel<<<(N + 3) / 4, 256, 0, stream>>>(h1, ss1, sd1, row_ptr, col, b1, h1e, N);

    // layer 2
    dim3 g2(256 / 64, (N + 63) / 64);
    sgemm64<<<g2, 256, 0, stream>>>(h1e, W2, h2, N, 256, 1024);
    s2_kernel<<<(N + 3) / 4, 256, 0, stream>>>(h2, as2, ad2, ss2, sd2, N);
    agg2_kernel<<<(N + 3) / 4, 256, 0, stream>>>(h2, ss2, sd2, row_ptr, col, b2, out_h, N);

    // outputs 2 & 3
    hipMemsetAsync(out_gf, 0, 256 * sizeof(float), stream);
    mean_kernel<<<80, 256, 0, stream>>>(out_h, out_gf, N);
    infl_kernel<<<(N + 3) / 4, 128, 0, stream>>>(out_h, Wp1, bp1, Wp2, bp2, out_if, N);
}

// Round 2
// 692.943 us; speedup vs baseline: 1.5104x; 1.5104x over previous
//
#include <hip/hip_runtime.h>

#define NEG_SLOPE 0.2f

typedef __bf16 bf16x8 __attribute__((ext_vector_type(8)));
typedef float floatx4 __attribute__((ext_vector_type(4)));
typedef unsigned short ushortx4 __attribute__((ext_vector_type(4)));

__device__ __forceinline__ float eluf(float x) { return x > 0.f ? x : __expf(x) - 1.f; }
__device__ __forceinline__ float lrelu(float x) { return x > 0.f ? x : NEG_SLOPE * x; }

__device__ __forceinline__ unsigned short f2bf(float f) {
    unsigned u = __float_as_uint(f);
    u += 0x7FFFu + ((u >> 16) & 1u);           // round-to-nearest-even
    return (unsigned short)(u >> 16);
}
__device__ __forceinline__ float bf2f(unsigned short h) {
    return __uint_as_float(((unsigned)h) << 16);
}
__device__ __forceinline__ void store_split4(unsigned short* hp, unsigned short* lp, float4 o) {
    ushortx4 hv, lv;
    hv[0] = f2bf(o.x); lv[0] = f2bf(o.x - bf2f(hv[0]));
    hv[1] = f2bf(o.y); lv[1] = f2bf(o.y - bf2f(hv[1]));
    hv[2] = f2bf(o.z); lv[2] = f2bf(o.z - bf2f(hv[2]));
    hv[3] = f2bf(o.w); lv[3] = f2bf(o.w - bf2f(hv[3]));
    *(ushortx4*)hp = hv;
    *(ushortx4*)lp = lv;
}

// ---------------- CSR build (dst-sorted adjacency, self-loops appended) ----------------
__global__ void count_kernel(const int* __restrict__ ei, int E, int N, int* __restrict__ counts) {
    int i = blockIdx.x * blockDim.x + threadIdx.x;
    int Et = E + N;
    if (i >= Et) return;
    int d = (i < E) ? ei[E + i] : (i - E);
    atomicAdd(&counts[d], 1);
}

__global__ void scan_kernel(int* __restrict__ counts_cursor, int* __restrict__ row_ptr, int N) {
    __shared__ int sdata[1024];
    __shared__ int s_carry;
    int t = threadIdx.x;
    if (t == 0) { s_carry = 0; row_ptr[0] = 0; }
    __syncthreads();
    for (int start = 0; start < N; start += 1024) {
        int i = start + t;
        int v = (i < N) ? counts_cursor[i] : 0;
        sdata[t] = v;
        __syncthreads();
        for (int d = 1; d < 1024; d <<= 1) {
            int add = (t >= d) ? sdata[t - d] : 0;
            __syncthreads();
            sdata[t] += add;
            __syncthreads();
        }
        int incl = sdata[t] + s_carry;
        if (i < N) { row_ptr[i + 1] = incl; counts_cursor[i] = incl - v; }
        __syncthreads();
        if (t == 1023) s_carry = incl;
        __syncthreads();
    }
}

__global__ void fill_kernel(const int* __restrict__ ei, int E, int N,
                            int* __restrict__ cursor, int* __restrict__ col) {
    int i = blockIdx.x * blockDim.x + threadIdx.x;
    int Et = E + N;
    if (i >= Et) return;
    int s, d;
    if (i < E) { s = ei[i]; d = ei[E + i]; } else { s = d = i - E; }
    int pos = atomicAdd(&cursor[d], 1);
    col[pos] = s;
}

// ---------------- fp32 -> bf16 hi/lo split, elementwise ----------------
__global__ void convert_split(const float* __restrict__ in, unsigned short* __restrict__ hi,
                              unsigned short* __restrict__ lo, int len4) {
    int i = blockIdx.x * blockDim.x + threadIdx.x;
    if (i >= len4) return;
    float4 v = ((const float4*)in)[i];
    store_split4(hi + (size_t)i * 4, lo + (size_t)i * 4, v);
}

// ---------------- transpose + split: B[K][N] fp32 -> T[N][K] bf16 hi/lo ----------------
__global__ __launch_bounds__(256) void transpose_split(const float* __restrict__ B,
        unsigned short* __restrict__ Th, unsigned short* __restrict__ Tl, int K, int N) {
    __shared__ float tile[32][33];
    int n0 = blockIdx.x * 32, k0 = blockIdx.y * 32;
    int tx = threadIdx.x, ty = threadIdx.y;  // block (32, 8)
    #pragma unroll
    for (int i = 0; i < 32; i += 8)
        tile[ty + i][tx] = B[(size_t)(k0 + ty + i) * N + n0 + tx];
    __syncthreads();
    #pragma unroll
    for (int i = 0; i < 32; i += 8) {
        float v = tile[tx][ty + i];
        unsigned short h = f2bf(v);
        unsigned short l = f2bf(v - bf2f(h));
        size_t idx = (size_t)(n0 + ty + i) * K + k0 + tx;
        Th[idx] = h; Tl[idx] = l;
    }
}

// ---------------- split-bf16 MFMA GEMM: C[M,N] = (Ah+Al)[M,K] @ (Bh+Bl)^T ----------------
// A arrays row-major [M][K] bf16 bits; B arrays row-major [N][K] (i.e. B^T); C fp32 [M][N].
// 128x128 tile, BK=32, 256 threads = 4 waves of 64x64, mfma_f32_16x16x32_bf16, 3-term split.
#define LDK 40  // 32 + 8 pad (shorts) -> 80 B row stride, 2-way (free) frag-read conflicts
__global__ __launch_bounds__(256) void gemm_bf16s(
        const unsigned short* __restrict__ Ah, const unsigned short* __restrict__ Al,
        const unsigned short* __restrict__ Bh, const unsigned short* __restrict__ Bl,
        float* __restrict__ C, int M, int N, int K) {
    __shared__ unsigned short As[2][128 * LDK];
    __shared__ unsigned short Bs[2][128 * LDK];
    int t = threadIdx.x;
    int lane = t & 63;
    int wave = t >> 6;
    int wm = (wave >> 1) * 64, wn = (wave & 1) * 64;
    int q = lane >> 4, l16 = lane & 15;
    int row0 = blockIdx.y * 128, col0 = blockIdx.x * 128;

    floatx4 acc[4][4] = {};

    int sg = (t & 7) * 4;   // k-offset in shorts (4-short granule, 8 B)
    int sr = t >> 3;        // row 0..31; 4 passes cover 128 rows

    for (int kt = 0; kt < K; kt += 32) {
        #pragma unroll
        for (int p = 0; p < 4; p++) {
            int r = sr + p * 32;
            int ga = min(row0 + r, M - 1);        // clamp ragged M (stores are guarded)
            size_t goff = (size_t)ga * K + kt + sg;
            ushortx4 vah = *(const ushortx4*)(Ah + goff);
            ushortx4 val = *(const ushortx4*)(Al + goff);
            size_t gob = (size_t)(col0 + r) * K + kt + sg;  // N is a multiple of 128
            ushortx4 vbh = *(const ushortx4*)(Bh + gob);
            ushortx4 vbl = *(const ushortx4*)(Bl + gob);
            int li = r * LDK + sg;
            *(ushortx4*)&As[0][li] = vah;
            *(ushortx4*)&As[1][li] = val;
            *(ushortx4*)&Bs[0][li] = vbh;
            *(ushortx4*)&Bs[1][li] = vbl;
        }
        __syncthreads();
        bf16x8 af[4][2], bf[4][2];
        #pragma unroll
        for (int i = 0; i < 4; i++) {
            af[i][0] = *(const bf16x8*)&As[0][(wm + i * 16 + l16) * LDK + q * 8];
            af[i][1] = *(const bf16x8*)&As[1][(wm + i * 16 + l16) * LDK + q * 8];
            bf[i][0] = *(const bf16x8*)&Bs[0][(wn + i * 16 + l16) * LDK + q * 8];
            bf[i][1] = *(const bf16x8*)&Bs[1][(wn + i * 16 + l16) * LDK + q * 8];
        }
        #pragma unroll
        for (int i = 0; i < 4; i++)
            #pragma unroll
            for (int j = 0; j < 4; j++) {
                acc[i][j] = __builtin_amdgcn_mfma_f32_16x16x32_bf16(af[i][0], bf[j][0], acc[i][j], 0, 0, 0);
                acc[i][j] = __builtin_amdgcn_mfma_f32_16x16x32_bf16(af[i][1], bf[j][0], acc[i][j], 0, 0, 0);
                acc[i][j] = __builtin_amdgcn_mfma_f32_16x16x32_bf16(af[i][0], bf[j][1], acc[i][j], 0, 0, 0);
            }
        __syncthreads();
    }
    #pragma unroll
    for (int i = 0; i < 4; i++) {
        #pragma unroll
        for (int r = 0; r < 4; r++) {
            int grow = row0 + wm + i * 16 + q * 4 + r;
            if (grow < M) {
                float* cp = C + (size_t)grow * N + col0 + wn + l16;
                cp[0]  = acc[i][0][r];
                cp[16] = acc[i][1][r];
                cp[32] = acc[i][2][r];
                cp[48] = acc[i][3][r];
            }
        }
    }
}

// ---------------- per-node attention logits, layer 1 (H=4, C=256) ----------------
__global__ void s1_kernel(const float* __restrict__ h1, const float* __restrict__ a_src,
                          const float* __restrict__ a_dst, float* __restrict__ ssrc,
                          float* __restrict__ sdst, int N) {
    int wid = (blockIdx.x * blockDim.x + threadIdx.x) >> 6;
    int lane = threadIdx.x & 63;
    if (wid >= N) return;
    const float* row = h1 + (size_t)wid * 1024;
    float aS[4] = {0, 0, 0, 0}, aD[4] = {0, 0, 0, 0};
    #pragma unroll
    for (int k = 0; k < 16; k++) {
        int c = k * 64 + lane;
        float v = row[c];
        int h = k >> 2;
        aS[h] += v * a_src[c];
        aD[h] += v * a_dst[c];
    }
    #pragma unroll
    for (int h = 0; h < 4; h++) {
        float s = aS[h], d = aD[h];
        for (int off = 32; off; off >>= 1) { s += __shfl_xor(s, off); d += __shfl_xor(d, off); }
        if (lane == 0) { ssrc[wid * 4 + h] = s; sdst[wid * 4 + h] = d; }
    }
}

// ---------------- per-node attention logits, layer 2 (H=1, C=256) ----------------
__global__ void s2_kernel(const float* __restrict__ h2, const float* __restrict__ a_src,
                          const float* __restrict__ a_dst, float* __restrict__ ssrc,
                          float* __restrict__ sdst, int N) {
    int wid = (blockIdx.x * blockDim.x + threadIdx.x) >> 6;
    int lane = threadIdx.x & 63;
    if (wid >= N) return;
    const float4* row = (const float4*)(h2 + (size_t)wid * 256);
    const float4* as4 = (const float4*)a_src;
    const float4* ad4 = (const float4*)a_dst;
    float4 v = row[lane], a = as4[lane], d = ad4[lane];
    float s = v.x * a.x + v.y * a.y + v.z * a.z + v.w * a.w;
    float t = v.x * d.x + v.y * d.y + v.z * d.z + v.w * d.w;
    for (int off = 32; off; off >>= 1) { s += __shfl_xor(s, off); t += __shfl_xor(t, off); }
    if (lane == 0) { ssrc[wid] = s; sdst[wid] = t; }
}

// ---------------- layer-1 aggregation (H=4, C=256); writes bf16 hi/lo for GEMM2 ----------------
__global__ __launch_bounds__(256) void agg1_kernel(const float* __restrict__ h1,
        const float* __restrict__ ssrc, const float* __restrict__ sdst,
        const int* __restrict__ row_ptr, const int* __restrict__ col,
        const float* __restrict__ bias,
        unsigned short* __restrict__ outh, unsigned short* __restrict__ outl, int N) {
    int wid = (blockIdx.x * blockDim.x + threadIdx.x) >> 6;
    int lane = threadIdx.x & 63;
    if (wid >= N) return;
    int base = row_ptr[wid];
    int deg = row_ptr[wid + 1] - base;
    float sd0 = sdst[wid * 4 + 0], sd1 = sdst[wid * 4 + 1];
    float sd2 = sdst[wid * 4 + 2], sd3 = sdst[wid * 4 + 3];
    float m0 = -1e30f, m1 = -1e30f, m2 = -1e30f, m3 = -1e30f;
    for (int i = lane; i < deg; i += 64) {
        int s = col[base + i];
        const float* sp = ssrc + s * 4;
        m0 = fmaxf(m0, lrelu(sp[0] + sd0));
        m1 = fmaxf(m1, lrelu(sp[1] + sd1));
        m2 = fmaxf(m2, lrelu(sp[2] + sd2));
        m3 = fmaxf(m3, lrelu(sp[3] + sd3));
    }
    #pragma unroll
    for (int off = 32; off; off >>= 1) {
        m0 = fmaxf(m0, __shfl_xor(m0, off));
        m1 = fmaxf(m1, __shfl_xor(m1, off));
        m2 = fmaxf(m2, __shfl_xor(m2, off));
        m3 = fmaxf(m3, __shfl_xor(m3, off));
    }
    float4 a0 = {0,0,0,0}, a1 = {0,0,0,0}, a2 = {0,0,0,0}, a3 = {0,0,0,0};
    float d0 = 0.f, d1 = 0.f, d2 = 0.f, d3 = 0.f;
    for (int i = 0; i < deg; i++) {
        int s = col[base + i];
        const float* sp = ssrc + s * 4;
        float x0 = __expf(lrelu(sp[0] + sd0) - m0); d0 += x0;
        float x1 = __expf(lrelu(sp[1] + sd1) - m1); d1 += x1;
        float x2 = __expf(lrelu(sp[2] + sd2) - m2); d2 += x2;
        float x3 = __expf(lrelu(sp[3] + sd3) - m3); d3 += x3;
        const float4* row = (const float4*)(h1 + (size_t)s * 1024);
        float4 v;
        v = row[lane];       a0.x += x0 * v.x; a0.y += x0 * v.y; a0.z += x0 * v.z; a0.w += x0 * v.w;
        v = row[64 + lane];  a1.x += x1 * v.x; a1.y += x1 * v.y; a1.z += x1 * v.z; a1.w += x1 * v.w;
        v = row[128 + lane]; a2.x += x2 * v.x; a2.y += x2 * v.y; a2.z += x2 * v.z; a2.w += x2 * v.w;
        v = row[192 + lane]; a3.x += x3 * v.x; a3.y += x3 * v.y; a3.z += x3 * v.z; a3.w += x3 * v.w;
    }
    float i0 = 1.f / (d0 + 1e-16f), i1 = 1.f / (d1 + 1e-16f);
    float i2 = 1.f / (d2 + 1e-16f), i3 = 1.f / (d3 + 1e-16f);
    size_t ob = (size_t)wid * 1024;
    int c = lane * 4;
    float4 o;
    o.x = eluf(a0.x * i0 + bias[c + 0]); o.y = eluf(a0.y * i0 + bias[c + 1]);
    o.z = eluf(a0.z * i0 + bias[c + 2]); o.w = eluf(a0.w * i0 + bias[c + 3]);
    store_split4(outh + ob + c, outl + ob + c, o);
    o.x = eluf(a1.x * i1 + bias[256 + c + 0]); o.y = eluf(a1.y * i1 + bias[256 + c + 1]);
    o.z = eluf(a1.z * i1 + bias[256 + c + 2]); o.w = eluf(a1.w * i1 + bias[256 + c + 3]);
    store_split4(outh + ob + 256 + c, outl + ob + 256 + c, o);
    o.x = eluf(a2.x * i2 + bias[512 + c + 0]); o.y = eluf(a2.y * i2 + bias[512 + c + 1]);
    o.z = eluf(a2.z * i2 + bias[512 + c + 2]); o.w = eluf(a2.w * i2 + bias[512 + c + 3]);
    store_split4(outh + ob + 512 + c, outl + ob + 512 + c, o);
    o.x = eluf(a3.x * i3 + bias[768 + c + 0]); o.y = eluf(a3.y * i3 + bias[768 + c + 1]);
    o.z = eluf(a3.z * i3 + bias[768 + c + 2]); o.w = eluf(a3.w * i3 + bias[768 + c + 3]);
    store_split4(outh + ob + 768 + c, outl + ob + 768 + c, o);
}

// ---------------- layer-2 aggregation (H=1, C=256) ----------------
__global__ __launch_bounds__(256) void agg2_kernel(const float* __restrict__ h2,
        const float* __restrict__ ssrc, const float* __restrict__ sdst,
        const int* __restrict__ row_ptr, const int* __restrict__ col,
        const float* __restrict__ bias, float* __restrict__ out, int N) {
    int wid = (blockIdx.x * blockDim.x + threadIdx.x) >> 6;
    int lane = threadIdx.x & 63;
    if (wid >= N) return;
    int base = row_ptr[wid];
    int deg = row_ptr[wid + 1] - base;
    float sd = sdst[wid];
    float m = -1e30f;
    for (int i = lane; i < deg; i += 64) {
        int s = col[base + i];
        m = fmaxf(m, lrelu(ssrc[s] + sd));
    }
    #pragma unroll
    for (int off = 32; off; off >>= 1) m = fmaxf(m, __shfl_xor(m, off));
    float4 a = {0,0,0,0};
    float den = 0.f;
    for (int i = 0; i < deg; i++) {
        int s = col[base + i];
        float x = __expf(lrelu(ssrc[s] + sd) - m); den += x;
        float4 v = ((const float4*)(h2 + (size_t)s * 256))[lane];
        a.x += x * v.x; a.y += x * v.y; a.z += x * v.z; a.w += x * v.w;
    }
    float inv = 1.f / (den + 1e-16f);
    int c = lane * 4;
    float4 o;
    o.x = eluf(a.x * inv + bias[c + 0]);
    o.y = eluf(a.y * inv + bias[c + 1]);
    o.z = eluf(a.z * inv + bias[c + 2]);
    o.w = eluf(a.w * inv + bias[c + 3]);
    *(float4*)(out + (size_t)wid * 256 + c) = o;
}

// ---------------- mean over nodes -> graph_features [256] ----------------
__global__ void mean_kernel(const float* __restrict__ h, float* __restrict__ gf, int N) {
    int c = threadIdx.x;
    int per = (N + gridDim.x - 1) / gridDim.x;
    int n0 = blockIdx.x * per;
    int n1 = min(N, n0 + per);
    float acc = 0.f;
    for (int n = n0; n < n1; n++) acc += h[(size_t)n * 256 + c];
    atomicAdd(&gf[c], acc * (1.0f / N));
}

// ---------------- influence head: sigmoid(relu(h@Wp1+bp1)@Wp2+bp2), 4 nodes/block ----------------
__global__ __launch_bounds__(128) void infl_kernel(const float* __restrict__ h,
        const float* __restrict__ Wp1, const float* __restrict__ bp1,
        const float* __restrict__ Wp2, const float* __restrict__ bp2,
        float* __restrict__ infl, int N) {
    __shared__ float sh[4][256];
    __shared__ float red[4][128];
    int nb = blockIdx.x * 4;
    int t = threadIdx.x;
    #pragma unroll
    for (int r = 0; r < 4; r++) {
        int n = nb + r;
        if (n < N) {
            sh[r][t] = h[(size_t)n * 256 + t];
            sh[r][t + 128] = h[(size_t)n * 256 + t + 128];
        }
    }
    __syncthreads();
    float acc0 = bp1[t], acc1 = acc0, acc2 = acc0, acc3 = acc0;
    for (int k = 0; k < 256; k++) {
        float w = Wp1[k * 128 + t];
        acc0 += sh[0][k] * w;
        acc1 += sh[1][k] * w;
        acc2 += sh[2][k] * w;
        acc3 += sh[3][k] * w;
    }
    float w2 = Wp2[t];
    red[0][t] = fmaxf(acc0, 0.f) * w2;
    red[1][t] = fmaxf(acc1, 0.f) * w2;
    red[2][t] = fmaxf(acc2, 0.f) * w2;
    red[3][t] = fmaxf(acc3, 0.f) * w2;
    __syncthreads();
    for (int s = 64; s > 0; s >>= 1) {
        if (t < s) {
            red[0][t] += red[0][t + s];
            red[1][t] += red[1][t + s];
            red[2][t] += red[2][t + s];
            red[3][t] += red[3][t + s];
        }
        __syncthreads();
    }
    if (t < 4) {
        int n = nb + t;
        if (n < N) {
            float v = red[t][0] + bp2[0];
            infl[n] = 1.f / (1.f + __expf(-v));
        }
    }
}

extern "C" void kernel_launch(void* const* d_in, const int* in_sizes, int n_in,
                              void* d_out, int out_size, void* d_ws, size_t ws_size,
                              hipStream_t stream) {
    const float* x   = (const float*)d_in[0];
    const int*   ei  = (const int*)d_in[1];
    const float* W1  = (const float*)d_in[2];
    const float* as1 = (const float*)d_in[3];
    const float* ad1 = (const float*)d_in[4];
    const float* b1  = (const float*)d_in[5];
    const float* W2  = (const float*)d_in[6];
    const float* as2 = (const float*)d_in[7];
    const float* ad2 = (const float*)d_in[8];
    const float* b2  = (const float*)d_in[9];
    const float* Wp1 = (const float*)d_in[10];
    const float* bp1 = (const float*)d_in[11];
    const float* Wp2 = (const float*)d_in[12];
    const float* bp2 = (const float*)d_in[13];

    const int N  = in_sizes[0] / 384;   // 20000
    const int E  = in_sizes[1] / 2;     // 320000
    const int Et = E + N;

    // ---- workspace layout (with stream-ordered aliasing to stay ~170 MB) ----
    char* wsp = (char*)d_ws;
    float* h1 = (float*)wsp;                       // [N,1024] fp32 (GEMM1 out)
    float* h2 = h1;                                // alias: h1 dead before GEMM2 writes
    wsp += (size_t)N * 1024 * sizeof(float);
    unsigned short* h1eh = (unsigned short*)wsp;   // [N,1024] bf16-hi (agg1 out)
    unsigned short* xh   = h1eh;                   // alias: x-split dead before agg1 writes
    wsp += (size_t)N * 1024 * sizeof(short);
    unsigned short* h1el = (unsigned short*)wsp;   // [N,1024] bf16-lo
    unsigned short* xl   = h1el;
    wsp += (size_t)N * 1024 * sizeof(short);
    unsigned short* w1th = (unsigned short*)wsp; wsp += (size_t)1024 * 384 * sizeof(short);
    unsigned short* w1tl = (unsigned short*)wsp; wsp += (size_t)1024 * 384 * sizeof(short);
    unsigned short* w2th = (unsigned short*)wsp; wsp += (size_t)256 * 1024 * sizeof(short);
    unsigned short* w2tl = (unsigned short*)wsp; wsp += (size_t)256 * 1024 * sizeof(short);
    float* ss1 = (float*)wsp; wsp += (size_t)N * 4 * sizeof(float);
    float* sd1 = (float*)wsp; wsp += (size_t)N * 4 * sizeof(float);
    float* ss2 = (float*)wsp; wsp += (size_t)N * sizeof(float);
    float* sd2 = (float*)wsp; wsp += (size_t)N * sizeof(float);
    int* row_ptr = (int*)wsp; wsp += (size_t)(N + 1) * sizeof(int);
    int* cursor  = (int*)wsp; wsp += (size_t)N * sizeof(int);
    int* col     = (int*)wsp;

    float* out_h  = (float*)d_out;             // [N,256]
    float* out_gf = out_h + (size_t)N * 256;   // [256]
    float* out_if = out_gf + 256;              // [N]

    // CSR build
    hipMemsetAsync(cursor, 0, (size_t)N * sizeof(int), stream);
    count_kernel<<<(Et + 255) / 256, 256, 0, stream>>>(ei, E, N, cursor);
    scan_kernel<<<1, 1024, 0, stream>>>(cursor, row_ptr, N);
    fill_kernel<<<(Et + 255) / 256, 256, 0, stream>>>(ei, E, N, cursor, col);

    // weight prep (tiny) + x split
    convert_split<<<(N * 384 / 4 + 255) / 256, 256, 0, stream>>>(x, xh, xl, N * 384 / 4);
    transpose_split<<<dim3(1024 / 32, 384 / 32), dim3(32, 8), 0, stream>>>(W1, w1th, w1tl, 384, 1024);
    transpose_split<<<dim3(256 / 32, 1024 / 32), dim3(32, 8), 0, stream>>>(W2, w2th, w2tl, 1024, 256);

    // layer 1
    gemm_bf16s<<<dim3(1024 / 128, (N + 127) / 128), 256, 0, stream>>>(xh, xl, w1th, w1tl, h1, N, 1024, 384);
    s1_kernel<<<(N + 3) / 4, 256, 0, stream>>>(h1, as1, ad1, ss1, sd1, N);
    agg1_kernel<<<(N + 3) / 4, 256, 0, stream>>>(h1, ss1, sd1, row_ptr, col, b1, h1eh, h1el, N);

    // layer 2
    gemm_bf16s<<<dim3(256 / 128, (N + 127) / 128), 256, 0, stream>>>(h1eh, h1el, w2th, w2tl, h2, N, 256, 1024);
    s2_kernel<<<(N + 3) / 4, 256, 0, stream>>>(h2, as2, ad2, ss2, sd2, N);
    agg2_kernel<<<(N + 3) / 4, 256, 0, stream>>>(h2, ss2, sd2, row_ptr, col, b2, out_h, N);

    // outputs 2 & 3
    hipMemsetAsync(out_gf, 0, 256 * sizeof(float), stream);
    mean_kernel<<<80, 256, 0, stream>>>(out_h, out_gf, N);
    infl_kernel<<<(N + 3) / 4, 128, 0, stream>>>(out_h, Wp1, bp1, Wp2, bp2, out_if, N);
}

// Round 3
// 584.055 us; speedup vs baseline: 1.7920x; 1.1864x over previous
//
#include <hip/hip_runtime.h>

#define NEG_SLOPE 0.2f

typedef __bf16 bf16x8 __attribute__((ext_vector_type(8)));
typedef float floatx4 __attribute__((ext_vector_type(4)));
typedef unsigned short ushortx4 __attribute__((ext_vector_type(4)));

__device__ __forceinline__ float eluf(float x) { return x > 0.f ? x : __expf(x) - 1.f; }
__device__ __forceinline__ float lrelu(float x) { return x > 0.f ? x : NEG_SLOPE * x; }

__device__ __forceinline__ unsigned short f2bf(float f) {
    unsigned u = __float_as_uint(f);
    u += 0x7FFFu + ((u >> 16) & 1u);           // round-to-nearest-even
    return (unsigned short)(u >> 16);
}
__device__ __forceinline__ float bf2f(unsigned short h) {
    return __uint_as_float(((unsigned)h) << 16);
}
__device__ __forceinline__ void store_split4(unsigned short* hp, unsigned short* lp, float4 o) {
    ushortx4 hv, lv;
    hv[0] = f2bf(o.x); lv[0] = f2bf(o.x - bf2f(hv[0]));
    hv[1] = f2bf(o.y); lv[1] = f2bf(o.y - bf2f(hv[1]));
    hv[2] = f2bf(o.z); lv[2] = f2bf(o.z - bf2f(hv[2]));
    hv[3] = f2bf(o.w); lv[3] = f2bf(o.w - bf2f(hv[3]));
    *(ushortx4*)hp = hv;
    *(ushortx4*)lp = lv;
}

// ---------------- CSR build (dst-sorted adjacency, self-loops appended) ----------------
__global__ void count_kernel(const int* __restrict__ ei, int E, int N, int* __restrict__ counts) {
    int i = blockIdx.x * blockDim.x + threadIdx.x;
    int Et = E + N;
    if (i >= Et) return;
    int d = (i < E) ? ei[E + i] : (i - E);
    atomicAdd(&counts[d], 1);
}

__global__ void scan_kernel(int* __restrict__ counts_cursor, int* __restrict__ row_ptr, int N) {
    __shared__ int sdata[1024];
    __shared__ int s_carry;
    int t = threadIdx.x;
    if (t == 0) { s_carry = 0; row_ptr[0] = 0; }
    __syncthreads();
    for (int start = 0; start < N; start += 1024) {
        int i = start + t;
        int v = (i < N) ? counts_cursor[i] : 0;
        sdata[t] = v;
        __syncthreads();
        for (int d = 1; d < 1024; d <<= 1) {
            int add = (t >= d) ? sdata[t - d] : 0;
            __syncthreads();
            sdata[t] += add;
            __syncthreads();
        }
        int incl = sdata[t] + s_carry;
        if (i < N) { row_ptr[i + 1] = incl; counts_cursor[i] = incl - v; }
        __syncthreads();
        if (t == 1023) s_carry = incl;
        __syncthreads();
    }
}

__global__ void fill_kernel(const int* __restrict__ ei, int E, int N,
                            int* __restrict__ cursor, int* __restrict__ col) {
    int i = blockIdx.x * blockDim.x + threadIdx.x;
    int Et = E + N;
    if (i >= Et) return;
    int s, d;
    if (i < E) { s = ei[i]; d = ei[E + i]; } else { s = d = i - E; }
    int pos = atomicAdd(&cursor[d], 1);
    col[pos] = s;
}

// ---------------- fp32 -> bf16 hi/lo split, elementwise ----------------
__global__ void convert_split(const float* __restrict__ in, unsigned short* __restrict__ hi,
                              unsigned short* __restrict__ lo, int len4) {
    int i = blockIdx.x * blockDim.x + threadIdx.x;
    if (i >= len4) return;
    float4 v = ((const float4*)in)[i];
    store_split4(hi + (size_t)i * 4, lo + (size_t)i * 4, v);
}

// ---------------- transpose + split: B[K][N] fp32 -> T[N][K] bf16 hi/lo ----------------
__global__ __launch_bounds__(256) void transpose_split(const float* __restrict__ B,
        unsigned short* __restrict__ Th, unsigned short* __restrict__ Tl, int K, int N) {
    __shared__ float tile[32][33];
    int n0 = blockIdx.x * 32, k0 = blockIdx.y * 32;
    int tx = threadIdx.x, ty = threadIdx.y;  // block (32, 8)
    #pragma unroll
    for (int i = 0; i < 32; i += 8)
        tile[ty + i][tx] = B[(size_t)(k0 + ty + i) * N + n0 + tx];
    __syncthreads();
    #pragma unroll
    for (int i = 0; i < 32; i += 8) {
        float v = tile[tx][ty + i];
        unsigned short h = f2bf(v);
        unsigned short l = f2bf(v - bf2f(h));
        size_t idx = (size_t)(n0 + ty + i) * K + k0 + tx;
        Th[idx] = h; Tl[idx] = l;
    }
}

// ---------------- split-bf16 MFMA GEMM: C[M,N] = (Ah+Al)[M,K] @ (Bh+Bl)^T ----------------
// A arrays row-major [M][K] bf16 bits; B arrays row-major [N][K] (i.e. B^T).
// OUT_BF16: C stored as round-to-nearest bf16 bits; else fp32.
// 128x128 tile, BK=32, 256 threads = 4 waves of 64x64, mfma_f32_16x16x32_bf16, 3-term split.
#define LDK 40  // 32 + 8 pad (shorts) -> 80 B row stride, 2-way (free) frag-read conflicts
template <bool OUT_BF16>
__global__ __launch_bounds__(256) void gemm_bf16s(
        const unsigned short* __restrict__ Ah, const unsigned short* __restrict__ Al,
        const unsigned short* __restrict__ Bh, const unsigned short* __restrict__ Bl,
        void* __restrict__ Cout, int M, int N, int K) {
    __shared__ unsigned short As[2][128 * LDK];
    __shared__ unsigned short Bs[2][128 * LDK];
    int t = threadIdx.x;
    int lane = t & 63;
    int wave = t >> 6;
    int wm = (wave >> 1) * 64, wn = (wave & 1) * 64;
    int q = lane >> 4, l16 = lane & 15;
    int row0 = blockIdx.y * 128, col0 = blockIdx.x * 128;

    floatx4 acc[4][4] = {};

    int sg = (t & 7) * 4;   // k-offset in shorts (4-short granule, 8 B)
    int sr = t >> 3;        // row 0..31; 4 passes cover 128 rows

    for (int kt = 0; kt < K; kt += 32) {
        #pragma unroll
        for (int p = 0; p < 4; p++) {
            int r = sr + p * 32;
            int ga = min(row0 + r, M - 1);        // clamp ragged M (stores are guarded)
            size_t goff = (size_t)ga * K + kt + sg;
            ushortx4 vah = *(const ushortx4*)(Ah + goff);
            ushortx4 val = *(const ushortx4*)(Al + goff);
            size_t gob = (size_t)(col0 + r) * K + kt + sg;  // N is a multiple of 128
            ushortx4 vbh = *(const ushortx4*)(Bh + gob);
            ushortx4 vbl = *(const ushortx4*)(Bl + gob);
            int li = r * LDK + sg;
            *(ushortx4*)&As[0][li] = vah;
            *(ushortx4*)&As[1][li] = val;
            *(ushortx4*)&Bs[0][li] = vbh;
            *(ushortx4*)&Bs[1][li] = vbl;
        }
        __syncthreads();
        bf16x8 af[4][2], bf[4][2];
        #pragma unroll
        for (int i = 0; i < 4; i++) {
            af[i][0] = *(const bf16x8*)&As[0][(wm + i * 16 + l16) * LDK + q * 8];
            af[i][1] = *(const bf16x8*)&As[1][(wm + i * 16 + l16) * LDK + q * 8];
            bf[i][0] = *(const bf16x8*)&Bs[0][(wn + i * 16 + l16) * LDK + q * 8];
            bf[i][1] = *(const bf16x8*)&Bs[1][(wn + i * 16 + l16) * LDK + q * 8];
        }
        #pragma unroll
        for (int i = 0; i < 4; i++)
            #pragma unroll
            for (int j = 0; j < 4; j++) {
                acc[i][j] = __builtin_amdgcn_mfma_f32_16x16x32_bf16(af[i][0], bf[j][0], acc[i][j], 0, 0, 0);
                acc[i][j] = __builtin_amdgcn_mfma_f32_16x16x32_bf16(af[i][1], bf[j][0], acc[i][j], 0, 0, 0);
                acc[i][j] = __builtin_amdgcn_mfma_f32_16x16x32_bf16(af[i][0], bf[j][1], acc[i][j], 0, 0, 0);
            }
        __syncthreads();
    }
    #pragma unroll
    for (int i = 0; i < 4; i++) {
        #pragma unroll
        for (int r = 0; r < 4; r++) {
            int grow = row0 + wm + i * 16 + q * 4 + r;
            if (grow < M) {
                if constexpr (OUT_BF16) {
                    unsigned short* cp = (unsigned short*)Cout + (size_t)grow * N + col0 + wn + l16;
                    cp[0]  = f2bf(acc[i][0][r]);
                    cp[16] = f2bf(acc[i][1][r]);
                    cp[32] = f2bf(acc[i][2][r]);
                    cp[48] = f2bf(acc[i][3][r]);
                } else {
                    float* cp = (float*)Cout + (size_t)grow * N + col0 + wn + l16;
                    cp[0]  = acc[i][0][r];
                    cp[16] = acc[i][1][r];
                    cp[32] = acc[i][2][r];
                    cp[48] = acc[i][3][r];
                }
            }
        }
    }
}

// ---------------- per-node attention logits, layer 1 (H=4, C=256), bf16 h1 ----------------
__global__ void s1_kernel(const unsigned short* __restrict__ h1b, const float* __restrict__ a_src,
                          const float* __restrict__ a_dst, float* __restrict__ ssrc,
                          float* __restrict__ sdst, int N) {
    int wid = (blockIdx.x * blockDim.x + threadIdx.x) >> 6;
    int lane = threadIdx.x & 63;
    if (wid >= N) return;
    const unsigned short* row = h1b + (size_t)wid * 1024;
    #pragma unroll
    for (int h = 0; h < 4; h++) {
        ushortx4 v = *(const ushortx4*)(row + h * 256 + lane * 4);
        float4 a = ((const float4*)a_src)[h * 64 + lane];
        float4 d = ((const float4*)a_dst)[h * 64 + lane];
        float v0 = bf2f(v[0]), v1 = bf2f(v[1]), v2 = bf2f(v[2]), v3 = bf2f(v[3]);
        float s = v0 * a.x + v1 * a.y + v2 * a.z + v3 * a.w;
        float t = v0 * d.x + v1 * d.y + v2 * d.z + v3 * d.w;
        for (int off = 32; off; off >>= 1) { s += __shfl_xor(s, off); t += __shfl_xor(t, off); }
        if (lane == 0) { ssrc[wid * 4 + h] = s; sdst[wid * 4 + h] = t; }
    }
}

// ---------------- per-node attention logits, layer 2 (H=1, C=256) ----------------
__global__ void s2_kernel(const float* __restrict__ h2, const float* __restrict__ a_src,
                          const float* __restrict__ a_dst, float* __restrict__ ssrc,
                          float* __restrict__ sdst, int N) {
    int wid = (blockIdx.x * blockDim.x + threadIdx.x) >> 6;
    int lane = threadIdx.x & 63;
    if (wid >= N) return;
    const float4* row = (const float4*)(h2 + (size_t)wid * 256);
    const float4* as4 = (const float4*)a_src;
    const float4* ad4 = (const float4*)a_dst;
    float4 v = row[lane], a = as4[lane], d = ad4[lane];
    float s = v.x * a.x + v.y * a.y + v.z * a.z + v.w * a.w;
    float t = v.x * d.x + v.y * d.y + v.z * d.z + v.w * d.w;
    for (int off = 32; off; off >>= 1) { s += __shfl_xor(s, off); t += __shfl_xor(t, off); }
    if (lane == 0) { ssrc[wid] = s; sdst[wid] = t; }
}

// ---------------- layer-1 aggregation (H=4, C=256); bf16 gather; writes bf16 hi/lo ----------------
__global__ __launch_bounds__(256) void agg1_kernel(const unsigned short* __restrict__ h1b,
        const float* __restrict__ ssrc, const float* __restrict__ sdst,
        const int* __restrict__ row_ptr, const int* __restrict__ col,
        const float* __restrict__ bias,
        unsigned short* __restrict__ outh, unsigned short* __restrict__ outl, int N) {
    int wid = (blockIdx.x * blockDim.x + threadIdx.x) >> 6;
    int lane = threadIdx.x & 63;
    if (wid >= N) return;
    int base = row_ptr[wid];
    int deg = row_ptr[wid + 1] - base;
    float sd0 = sdst[wid * 4 + 0], sd1 = sdst[wid * 4 + 1];
    float sd2 = sdst[wid * 4 + 2], sd3 = sdst[wid * 4 + 3];
    float m0 = -1e30f, m1 = -1e30f, m2 = -1e30f, m3 = -1e30f;
    for (int i = lane; i < deg; i += 64) {
        int s = col[base + i];
        const float* sp = ssrc + s * 4;
        m0 = fmaxf(m0, lrelu(sp[0] + sd0));
        m1 = fmaxf(m1, lrelu(sp[1] + sd1));
        m2 = fmaxf(m2, lrelu(sp[2] + sd2));
        m3 = fmaxf(m3, lrelu(sp[3] + sd3));
    }
    #pragma unroll
    for (int off = 32; off; off >>= 1) {
        m0 = fmaxf(m0, __shfl_xor(m0, off));
        m1 = fmaxf(m1, __shfl_xor(m1, off));
        m2 = fmaxf(m2, __shfl_xor(m2, off));
        m3 = fmaxf(m3, __shfl_xor(m3, off));
    }
    float4 a0 = {0,0,0,0}, a1 = {0,0,0,0}, a2 = {0,0,0,0}, a3 = {0,0,0,0};
    float d0 = 0.f, d1 = 0.f, d2 = 0.f, d3 = 0.f;
    int c = lane * 4;
    for (int i = 0; i < deg; i++) {
        int s = col[base + i];
        const float* sp = ssrc + s * 4;
        float x0 = __expf(lrelu(sp[0] + sd0) - m0); d0 += x0;
        float x1 = __expf(lrelu(sp[1] + sd1) - m1); d1 += x1;
        float x2 = __expf(lrelu(sp[2] + sd2) - m2); d2 += x2;
        float x3 = __expf(lrelu(sp[3] + sd3) - m3); d3 += x3;
        const unsigned short* row = h1b + (size_t)s * 1024;
        ushortx4 v;
        v = *(const ushortx4*)(row + c);
        a0.x += x0 * bf2f(v[0]); a0.y += x0 * bf2f(v[1]); a0.z += x0 * bf2f(v[2]); a0.w += x0 * bf2f(v[3]);
        v = *(const ushortx4*)(row + 256 + c);
        a1.x += x1 * bf2f(v[0]); a1.y += x1 * bf2f(v[1]); a1.z += x1 * bf2f(v[2]); a1.w += x1 * bf2f(v[3]);
        v = *(const ushortx4*)(row + 512 + c);
        a2.x += x2 * bf2f(v[0]); a2.y += x2 * bf2f(v[1]); a2.z += x2 * bf2f(v[2]); a2.w += x2 * bf2f(v[3]);
        v = *(const ushortx4*)(row + 768 + c);
        a3.x += x3 * bf2f(v[0]); a3.y += x3 * bf2f(v[1]); a3.z += x3 * bf2f(v[2]); a3.w += x3 * bf2f(v[3]);
    }
    float i0 = 1.f / (d0 + 1e-16f), i1 = 1.f / (d1 + 1e-16f);
    float i2 = 1.f / (d2 + 1e-16f), i3 = 1.f / (d3 + 1e-16f);
    size_t ob = (size_t)wid * 1024;
    float4 o;
    o.x = eluf(a0.x * i0 + bias[c + 0]); o.y = eluf(a0.y * i0 + bias[c + 1]);
    o.z = eluf(a0.z * i0 + bias[c + 2]); o.w = eluf(a0.w * i0 + bias[c + 3]);
    store_split4(outh + ob + c, outl + ob + c, o);
    o.x = eluf(a1.x * i1 + bias[256 + c + 0]); o.y = eluf(a1.y * i1 + bias[256 + c + 1]);
    o.z = eluf(a1.z * i1 + bias[256 + c + 2]); o.w = eluf(a1.w * i1 + bias[256 + c + 3]);
    store_split4(outh + ob + 256 + c, outl + ob + 256 + c, o);
    o.x = eluf(a2.x * i2 + bias[512 + c + 0]); o.y = eluf(a2.y * i2 + bias[512 + c + 1]);
    o.z = eluf(a2.z * i2 + bias[512 + c + 2]); o.w = eluf(a2.w * i2 + bias[512 + c + 3]);
    store_split4(outh + ob + 512 + c, outl + ob + 512 + c, o);
    o.x = eluf(a3.x * i3 + bias[768 + c + 0]); o.y = eluf(a3.y * i3 + bias[768 + c + 1]);
    o.z = eluf(a3.z * i3 + bias[768 + c + 2]); o.w = eluf(a3.w * i3 + bias[768 + c + 3]);
    store_split4(outh + ob + 768 + c, outl + ob + 768 + c, o);
}

// ---------------- layer-2 aggregation (H=1, C=256) ----------------
__global__ __launch_bounds__(256) void agg2_kernel(const float* __restrict__ h2,
        const float* __restrict__ ssrc, const float* __restrict__ sdst,
        const int* __restrict__ row_ptr, const int* __restrict__ col,
        const float* __restrict__ bias, float* __restrict__ out, int N) {
    int wid = (blockIdx.x * blockDim.x + threadIdx.x) >> 6;
    int lane = threadIdx.x & 63;
    if (wid >= N) return;
    int base = row_ptr[wid];
    int deg = row_ptr[wid + 1] - base;
    float sd = sdst[wid];
    float m = -1e30f;
    for (int i = lane; i < deg; i += 64) {
        int s = col[base + i];
        m = fmaxf(m, lrelu(ssrc[s] + sd));
    }
    #pragma unroll
    for (int off = 32; off; off >>= 1) m = fmaxf(m, __shfl_xor(m, off));
    float4 a = {0,0,0,0};
    float den = 0.f;
    for (int i = 0; i < deg; i++) {
        int s = col[base + i];
        float x = __expf(lrelu(ssrc[s] + sd) - m); den += x;
        float4 v = ((const float4*)(h2 + (size_t)s * 256))[lane];
        a.x += x * v.x; a.y += x * v.y; a.z += x * v.z; a.w += x * v.w;
    }
    float inv = 1.f / (den + 1e-16f);
    int c = lane * 4;
    float4 o;
    o.x = eluf(a.x * inv + bias[c + 0]);
    o.y = eluf(a.y * inv + bias[c + 1]);
    o.z = eluf(a.z * inv + bias[c + 2]);
    o.w = eluf(a.w * inv + bias[c + 3]);
    *(float4*)(out + (size_t)wid * 256 + c) = o;
}

// ---------------- mean over nodes -> graph_features [256] ----------------
__global__ void mean_kernel(const float* __restrict__ h, float* __restrict__ gf, int N) {
    int c = threadIdx.x;
    int per = (N + gridDim.x - 1) / gridDim.x;
    int n0 = blockIdx.x * per;
    int n1 = min(N, n0 + per);
    float acc = 0.f;
    for (int n = n0; n < n1; n++) acc += h[(size_t)n * 256 + c];
    atomicAdd(&gf[c], acc * (1.0f / N));
}

// ---------------- influence head: sigmoid(relu(h@Wp1+bp1)@Wp2+bp2), 4 nodes/block ----------------
__global__ __launch_bounds__(128) void infl_kernel(const float* __restrict__ h,
        const float* __restrict__ Wp1, const float* __restrict__ bp1,
        const float* __restrict__ Wp2, const float* __restrict__ bp2,
        float* __restrict__ infl, int N) {
    __shared__ float sh[4][256];
    __shared__ float red[4][128];
    int nb = blockIdx.x * 4;
    int t = threadIdx.x;
    #pragma unroll
    for (int r = 0; r < 4; r++) {
        int n = nb + r;
        if (n < N) {
            sh[r][t] = h[(size_t)n * 256 + t];
            sh[r][t + 128] = h[(size_t)n * 256 + t + 128];
        }
    }
    __syncthreads();
    float acc0 = bp1[t], acc1 = acc0, acc2 = acc0, acc3 = acc0;
    for (int k = 0; k < 256; k++) {
        float w = Wp1[k * 128 + t];
        acc0 += sh[0][k] * w;
        acc1 += sh[1][k] * w;
        acc2 += sh[2][k] * w;
        acc3 += sh[3][k] * w;
    }
    float w2 = Wp2[t];
    red[0][t] = fmaxf(acc0, 0.f) * w2;
    red[1][t] = fmaxf(acc1, 0.f) * w2;
    red[2][t] = fmaxf(acc2, 0.f) * w2;
    red[3][t] = fmaxf(acc3, 0.f) * w2;
    __syncthreads();
    for (int s = 64; s > 0; s >>= 1) {
        if (t < s) {
            red[0][t] += red[0][t + s];
            red[1][t] += red[1][t + s];
            red[2][t] += red[2][t + s];
            red[3][t] += red[3][t + s];
        }
        __syncthreads();
    }
    if (t < 4) {
        int n = nb + t;
        if (n < N) {
            float v = red[t][0] + bp2[0];
            infl[n] = 1.f / (1.f + __expf(-v));
        }
    }
}

extern "C" void kernel_launch(void* const* d_in, const int* in_sizes, int n_in,
                              void* d_out, int out_size, void* d_ws, size_t ws_size,
                              hipStream_t stream) {
    const float* x   = (const float*)d_in[0];
    const int*   ei  = (const int*)d_in[1];
    const float* W1  = (const float*)d_in[2];
    const float* as1 = (const float*)d_in[3];
    const float* ad1 = (const float*)d_in[4];
    const float* b1  = (const float*)d_in[5];
    const float* W2  = (const float*)d_in[6];
    const float* as2 = (const float*)d_in[7];
    const float* ad2 = (const float*)d_in[8];
    const float* b2  = (const float*)d_in[9];
    const float* Wp1 = (const float*)d_in[10];
    const float* bp1 = (const float*)d_in[11];
    const float* Wp2 = (const float*)d_in[12];
    const float* bp2 = (const float*)d_in[13];

    const int N  = in_sizes[0] / 384;   // 20000
    const int E  = in_sizes[1] / 2;     // 320000
    const int Et = E + N;

    // ---- workspace layout (stream-ordered aliasing) ----
    char* wsp = (char*)d_ws;
    unsigned short* h1b = (unsigned short*)wsp;    // [N,1024] bf16 (GEMM1 out)
    float* h2 = (float*)wsp;                       // alias: h1b dead before GEMM2 writes ([N,256] fp32)
    wsp += (size_t)N * 1024 * sizeof(short);
    unsigned short* h1eh = (unsigned short*)wsp;   // [N,1024] bf16-hi (agg1 out)
    unsigned short* xh   = h1eh;                   // alias: x-split dead before agg1 writes
    wsp += (size_t)N * 1024 * sizeof(short);
    unsigned short* h1el = (unsigned short*)wsp;   // [N,1024] bf16-lo
    unsigned short* xl   = h1el;
    wsp += (size_t)N * 1024 * sizeof(short);
    unsigned short* w1th = (unsigned short*)wsp; wsp += (size_t)1024 * 384 * sizeof(short);
    unsigned short* w1tl = (unsigned short*)wsp; wsp += (size_t)1024 * 384 * sizeof(short);
    unsigned short* w2th = (unsigned short*)wsp; wsp += (size_t)256 * 1024 * sizeof(short);
    unsigned short* w2tl = (unsigned short*)wsp; wsp += (size_t)256 * 1024 * sizeof(short);
    float* ss1 = (float*)wsp; wsp += (size_t)N * 4 * sizeof(float);
    float* sd1 = (float*)wsp; wsp += (size_t)N * 4 * sizeof(float);
    float* ss2 = (float*)wsp; wsp += (size_t)N * sizeof(float);
    float* sd2 = (float*)wsp; wsp += (size_t)N * sizeof(float);
    int* row_ptr = (int*)wsp; wsp += (size_t)(N + 1) * sizeof(int);
    int* cursor  = (int*)wsp; wsp += (size_t)N * sizeof(int);
    int* col     = (int*)wsp;

    float* out_h  = (float*)d_out;             // [N,256]
    float* out_gf = out_h + (size_t)N * 256;   // [256]
    float* out_if = out_gf + 256;              // [N]

    // CSR build
    hipMemsetAsync(cursor, 0, (size_t)N * sizeof(int), stream);
    count_kernel<<<(Et + 255) / 256, 256, 0, stream>>>(ei, E, N, cursor);
    scan_kernel<<<1, 1024, 0, stream>>>(cursor, row_ptr, N);
    fill_kernel<<<(Et + 255) / 256, 256, 0, stream>>>(ei, E, N, cursor, col);

    // weight prep (tiny) + x split
    convert_split<<<(N * 384 / 4 + 255) / 256, 256, 0, stream>>>(x, xh, xl, N * 384 / 4);
    transpose_split<<<dim3(1024 / 32, 384 / 32), dim3(32, 8), 0, stream>>>(W1, w1th, w1tl, 384, 1024);
    transpose_split<<<dim3(256 / 32, 1024 / 32), dim3(32, 8), 0, stream>>>(W2, w2th, w2tl, 1024, 256);

    // layer 1 (h1 kept in bf16 for the edge gather)
    gemm_bf16s<true><<<dim3(1024 / 128, (N + 127) / 128), 256, 0, stream>>>(xh, xl, w1th, w1tl, h1b, N, 1024, 384);
    s1_kernel<<<(N + 3) / 4, 256, 0, stream>>>(h1b, as1, ad1, ss1, sd1, N);
    agg1_kernel<<<(N + 3) / 4, 256, 0, stream>>>(h1b, ss1, sd1, row_ptr, col, b1, h1eh, h1el, N);

    // layer 2
    gemm_bf16s<false><<<dim3(256 / 128, (N + 127) / 128), 256, 0, stream>>>(h1eh, h1el, w2th, w2tl, h2, N, 256, 1024);
    s2_kernel<<<(N + 3) / 4, 256, 0, stream>>>(h2, as2, ad2, ss2, sd2, N);
    agg2_kernel<<<(N + 3) / 4, 256, 0, stream>>>(h2, ss2, sd2, row_ptr, col, b2, out_h, N);

    // outputs 2 & 3
    hipMemsetAsync(out_gf, 0, 256 * sizeof(float), stream);
    mean_kernel<<<80, 256, 0, stream>>>(out_h, out_gf, N);
    infl_kernel<<<(N + 3) / 4, 128, 0, stream>>>(out_h, Wp1, bp1, Wp2, bp2, out_if, N);
}

// Round 4
// 530.700 us; speedup vs baseline: 1.9721x; 1.1005x over previous
//
#include <hip/hip_runtime.h>

#define NEG_SLOPE 0.2f

typedef __bf16 bf16x8 __attribute__((ext_vector_type(8)));
typedef float floatx4 __attribute__((ext_vector_type(4)));
typedef unsigned short ushortx4 __attribute__((ext_vector_type(4)));

__device__ __forceinline__ float eluf(float x) { return x > 0.f ? x : __expf(x) - 1.f; }
__device__ __forceinline__ float lrelu(float x) { return x > 0.f ? x : NEG_SLOPE * x; }

__device__ __forceinline__ unsigned short f2bf(float f) {
    unsigned u = __float_as_uint(f);
    u += 0x7FFFu + ((u >> 16) & 1u);           // round-to-nearest-even
    return (unsigned short)(u >> 16);
}
__device__ __forceinline__ float bf2f(unsigned short h) {
    return __uint_as_float(((unsigned)h) << 16);
}

// ---------------- CSR build (dst-sorted adjacency, self-loops appended) ----------------
__global__ void count_kernel(const int* __restrict__ ei, int E, int N, int* __restrict__ counts) {
    int i = blockIdx.x * blockDim.x + threadIdx.x;
    int Et = E + N;
    if (i >= Et) return;
    int d = (i < E) ? ei[E + i] : (i - E);
    atomicAdd(&counts[d], 1);
}

// single 1024-thread block; wave-shuffle scan (4 barriers/chunk vs 400 in the naive version)
__global__ void scan_kernel(int* __restrict__ counts_cursor, int* __restrict__ row_ptr, int N) {
    __shared__ int s_wsum[16];
    __shared__ int s_carry;
    int t = threadIdx.x;
    int lane = t & 63, wid = t >> 6;
    if (t == 0) { s_carry = 0; row_ptr[0] = 0; }
    __syncthreads();
    for (int start = 0; start < N; start += 1024) {
        int i = start + t;
        int v = (i < N) ? counts_cursor[i] : 0;
        int s = v;
        #pragma unroll
        for (int d = 1; d < 64; d <<= 1) {
            int u = __shfl_up(s, d);
            if (lane >= d) s += u;
        }
        if (lane == 63) s_wsum[wid] = s;
        __syncthreads();
        if (wid == 0) {
            int w = (lane < 16) ? s_wsum[lane] : 0;
            #pragma unroll
            for (int d = 1; d < 16; d <<= 1) {
                int u = __shfl_up(w, d);
                if (lane >= d) w += u;
            }
            if (lane < 16) s_wsum[lane] = w;
        }
        __syncthreads();
        int incl = s + (wid ? s_wsum[wid - 1] : 0) + s_carry;
        if (i < N) { row_ptr[i + 1] = incl; counts_cursor[i] = incl - v; }
        __syncthreads();
        if (t == 0) s_carry += s_wsum[15];
        __syncthreads();
    }
}

__global__ void fill_kernel(const int* __restrict__ ei, int E, int N,
                            int* __restrict__ cursor, int* __restrict__ col) {
    int i = blockIdx.x * blockDim.x + threadIdx.x;
    int Et = E + N;
    if (i >= Et) return;
    int s, d;
    if (i < E) { s = ei[i]; d = ei[E + i]; } else { s = d = i - E; }
    int pos = atomicAdd(&cursor[d], 1);
    col[pos] = s;
}

// ---------------- transpose + split: B[K][N] fp32 -> T[N][K] bf16 hi/lo ----------------
__global__ __launch_bounds__(256) void transpose_split(const float* __restrict__ B,
        unsigned short* __restrict__ Th, unsigned short* __restrict__ Tl, int K, int N) {
    __shared__ float tile[32][33];
    int n0 = blockIdx.x * 32, k0 = blockIdx.y * 32;
    int tx = threadIdx.x, ty = threadIdx.y;  // block (32, 8)
    #pragma unroll
    for (int i = 0; i < 32; i += 8)
        tile[ty + i][tx] = B[(size_t)(k0 + ty + i) * N + n0 + tx];
    __syncthreads();
    #pragma unroll
    for (int i = 0; i < 32; i += 8) {
        float v = tile[tx][ty + i];
        unsigned short h = f2bf(v);
        unsigned short l = f2bf(v - bf2f(h));
        size_t idx = (size_t)(n0 + ty + i) * K + k0 + tx;
        Th[idx] = h; Tl[idx] = l;
    }
}

// ---------------- 2-term split-bf16 MFMA GEMM: C = A_hi @ (Bh+Bl)^T ----------------
// A: fp32 [M][K] (converted in staging) or bf16 bits [M][K]. B arrays: [N][K] (B^T) hi/lo.
// 128xTN tile, BK=32, 256 threads = 4 waves; mfma_f32_16x16x32_bf16; 2 MFMA per frag.
#define LDK 40  // 32 + 8 pad (shorts) -> 80 B row stride, 2-way (free) frag-read conflicts
template <bool A_FP32, bool OUT_BF16, int TN>
__global__ __launch_bounds__(256) void gemm_2t(const void* __restrict__ Aptr,
        const unsigned short* __restrict__ Bh, const unsigned short* __restrict__ Bl,
        void* __restrict__ Cout, int M, int N, int K) {
    constexpr int JN = TN / 32;                  // B frags per wave (TN=128 -> 4, TN=64 -> 2)
    __shared__ unsigned short As[128 * LDK];
    __shared__ unsigned short Bs[2][TN * LDK];
    int t = threadIdx.x;
    int lane = t & 63, wave = t >> 6;
    int wm = (wave >> 1) * 64, wn = (wave & 1) * (TN / 2);
    int q = lane >> 4, l16 = lane & 15;
    int row0 = blockIdx.y * 128, col0 = blockIdx.x * TN;

    floatx4 acc[4][JN] = {};

    int sg = (t & 7) * 4;   // k-offset (4-elem granule)
    int sr = t >> 3;        // row 0..31 per pass

    for (int kt = 0; kt < K; kt += 32) {
        #pragma unroll
        for (int p = 0; p < 4; p++) {
            int r = sr + p * 32;
            int ga = min(row0 + r, M - 1);        // clamp ragged M (stores are guarded)
            int li = r * LDK + sg;
            if constexpr (A_FP32) {
                const float* ap = (const float*)Aptr + (size_t)ga * K + kt + sg;
                float4 va = *(const float4*)ap;
                ushortx4 vh;
                vh[0] = f2bf(va.x); vh[1] = f2bf(va.y); vh[2] = f2bf(va.z); vh[3] = f2bf(va.w);
                *(ushortx4*)&As[li] = vh;
            } else {
                const unsigned short* ap = (const unsigned short*)Aptr + (size_t)ga * K + kt + sg;
                *(ushortx4*)&As[li] = *(const ushortx4*)ap;
            }
        }
        #pragma unroll
        for (int p = 0; p < TN / 32; p++) {
            int r = sr + p * 32;
            size_t gob = (size_t)(col0 + r) * K + kt + sg;  // N multiple of TN
            *(ushortx4*)&Bs[0][r * LDK + sg] = *(const ushortx4*)(Bh + gob);
            *(ushortx4*)&Bs[1][r * LDK + sg] = *(const ushortx4*)(Bl + gob);
        }
        __syncthreads();
        bf16x8 af[4], bfr[JN][2];
        #pragma unroll
        for (int i = 0; i < 4; i++)
            af[i] = *(const bf16x8*)&As[(wm + i * 16 + l16) * LDK + q * 8];
        #pragma unroll
        for (int j = 0; j < JN; j++) {
            bfr[j][0] = *(const bf16x8*)&Bs[0][(wn + j * 16 + l16) * LDK + q * 8];
            bfr[j][1] = *(const bf16x8*)&Bs[1][(wn + j * 16 + l16) * LDK + q * 8];
        }
        #pragma unroll
        for (int i = 0; i < 4; i++)
            #pragma unroll
            for (int j = 0; j < JN; j++) {
                acc[i][j] = __builtin_amdgcn_mfma_f32_16x16x32_bf16(af[i], bfr[j][0], acc[i][j], 0, 0, 0);
                acc[i][j] = __builtin_amdgcn_mfma_f32_16x16x32_bf16(af[i], bfr[j][1], acc[i][j], 0, 0, 0);
            }
        __syncthreads();
    }
    #pragma unroll
    for (int i = 0; i < 4; i++) {
        #pragma unroll
        for (int r = 0; r < 4; r++) {
            int grow = row0 + wm + i * 16 + q * 4 + r;
            if (grow < M) {
                if constexpr (OUT_BF16) {
                    unsigned short* cp = (unsigned short*)Cout + (size_t)grow * N + col0 + wn + l16;
                    #pragma unroll
                    for (int j = 0; j < JN; j++) cp[j * 16] = f2bf(acc[i][j][r]);
                } else {
                    float* cp = (float*)Cout + (size_t)grow * N + col0 + wn + l16;
                    #pragma unroll
                    for (int j = 0; j < JN; j++) cp[j * 16] = acc[i][j][r];
                }
            }
        }
    }
}

// ---------------- per-node attention logits, layer 1 (H=4, C=256), bf16 h1 ----------------
__global__ void s1_kernel(const unsigned short* __restrict__ h1b, const float* __restrict__ a_src,
                          const float* __restrict__ a_dst, float* __restrict__ ssrc,
                          float* __restrict__ sdst, int N) {
    int wid = (blockIdx.x * blockDim.x + threadIdx.x) >> 6;
    int lane = threadIdx.x & 63;
    if (wid >= N) return;
    const unsigned short* row = h1b + (size_t)wid * 1024;
    #pragma unroll
    for (int h = 0; h < 4; h++) {
        ushortx4 v = *(const ushortx4*)(row + h * 256 + lane * 4);
        float4 a = ((const float4*)a_src)[h * 64 + lane];
        float4 d = ((const float4*)a_dst)[h * 64 + lane];
        float v0 = bf2f(v[0]), v1 = bf2f(v[1]), v2 = bf2f(v[2]), v3 = bf2f(v[3]);
        float s = v0 * a.x + v1 * a.y + v2 * a.z + v3 * a.w;
        float t = v0 * d.x + v1 * d.y + v2 * d.z + v3 * d.w;
        for (int off = 32; off; off >>= 1) { s += __shfl_xor(s, off); t += __shfl_xor(t, off); }
        if (lane == 0) { ssrc[wid * 4 + h] = s; sdst[wid * 4 + h] = t; }
    }
}

// ---------------- per-node attention logits, layer 2 (H=1, C=256), bf16 h2 ----------------
__global__ void s2_kernel(const unsigned short* __restrict__ h2b, const float* __restrict__ a_src,
                          const float* __restrict__ a_dst, float* __restrict__ ssrc,
                          float* __restrict__ sdst, int N) {
    int wid = (blockIdx.x * blockDim.x + threadIdx.x) >> 6;
    int lane = threadIdx.x & 63;
    if (wid >= N) return;
    ushortx4 v = *(const ushortx4*)(h2b + (size_t)wid * 256 + lane * 4);
    float4 a = ((const float4*)a_src)[lane];
    float4 d = ((const float4*)a_dst)[lane];
    float v0 = bf2f(v[0]), v1 = bf2f(v[1]), v2 = bf2f(v[2]), v3 = bf2f(v[3]);
    float s = v0 * a.x + v1 * a.y + v2 * a.z + v3 * a.w;
    float t = v0 * d.x + v1 * d.y + v2 * d.z + v3 * d.w;
    for (int off = 32; off; off >>= 1) { s += __shfl_xor(s, off); t += __shfl_xor(t, off); }
    if (lane == 0) { ssrc[wid] = s; sdst[wid] = t; }
}

// ---------------- layer-1 aggregation (H=4, C=256); bf16 gather -> bf16 out ----------------
__global__ __launch_bounds__(256) void agg1_kernel(const unsigned short* __restrict__ h1b,
        const float* __restrict__ ssrc, const float* __restrict__ sdst,
        const int* __restrict__ row_ptr, const int* __restrict__ col,
        const float* __restrict__ bias, unsigned short* __restrict__ outb, int N) {
    int wid = (blockIdx.x * blockDim.x + threadIdx.x) >> 6;
    int lane = threadIdx.x & 63;
    if (wid >= N) return;
    int base = row_ptr[wid];
    int deg = row_ptr[wid + 1] - base;
    float sd0 = sdst[wid * 4 + 0], sd1 = sdst[wid * 4 + 1];
    float sd2 = sdst[wid * 4 + 2], sd3 = sdst[wid * 4 + 3];
    float m0 = -1e30f, m1 = -1e30f, m2 = -1e30f, m3 = -1e30f;
    for (int i = lane; i < deg; i += 64) {
        int s = col[base + i];
        const float* sp = ssrc + s * 4;
        m0 = fmaxf(m0, lrelu(sp[0] + sd0));
        m1 = fmaxf(m1, lrelu(sp[1] + sd1));
        m2 = fmaxf(m2, lrelu(sp[2] + sd2));
        m3 = fmaxf(m3, lrelu(sp[3] + sd3));
    }
    #pragma unroll
    for (int off = 32; off; off >>= 1) {
        m0 = fmaxf(m0, __shfl_xor(m0, off));
        m1 = fmaxf(m1, __shfl_xor(m1, off));
        m2 = fmaxf(m2, __shfl_xor(m2, off));
        m3 = fmaxf(m3, __shfl_xor(m3, off));
    }
    float4 a0 = {0,0,0,0}, a1 = {0,0,0,0}, a2 = {0,0,0,0}, a3 = {0,0,0,0};
    float d0 = 0.f, d1 = 0.f, d2 = 0.f, d3 = 0.f;
    int c = lane * 4;
    for (int i = 0; i < deg; i++) {
        int s = col[base + i];
        const float* sp = ssrc + s * 4;
        float x0 = __expf(lrelu(sp[0] + sd0) - m0); d0 += x0;
        float x1 = __expf(lrelu(sp[1] + sd1) - m1); d1 += x1;
        float x2 = __expf(lrelu(sp[2] + sd2) - m2); d2 += x2;
        float x3 = __expf(lrelu(sp[3] + sd3) - m3); d3 += x3;
        const unsigned short* row = h1b + (size_t)s * 1024;
        ushortx4 v;
        v = *(const ushortx4*)(row + c);
        a0.x += x0 * bf2f(v[0]); a0.y += x0 * bf2f(v[1]); a0.z += x0 * bf2f(v[2]); a0.w += x0 * bf2f(v[3]);
        v = *(const ushortx4*)(row + 256 + c);
        a1.x += x1 * bf2f(v[0]); a1.y += x1 * bf2f(v[1]); a1.z += x1 * bf2f(v[2]); a1.w += x1 * bf2f(v[3]);
        v = *(const ushortx4*)(row + 512 + c);
        a2.x += x2 * bf2f(v[0]); a2.y += x2 * bf2f(v[1]); a2.z += x2 * bf2f(v[2]); a2.w += x2 * bf2f(v[3]);
        v = *(const ushortx4*)(row + 768 + c);
        a3.x += x3 * bf2f(v[0]); a3.y += x3 * bf2f(v[1]); a3.z += x3 * bf2f(v[2]); a3.w += x3 * bf2f(v[3]);
    }
    float i0 = 1.f / (d0 + 1e-16f), i1 = 1.f / (d1 + 1e-16f);
    float i2 = 1.f / (d2 + 1e-16f), i3 = 1.f / (d3 + 1e-16f);
    size_t ob = (size_t)wid * 1024;
    ushortx4 w;
    w[0] = f2bf(eluf(a0.x * i0 + bias[c + 0])); w[1] = f2bf(eluf(a0.y * i0 + bias[c + 1]));
    w[2] = f2bf(eluf(a0.z * i0 + bias[c + 2])); w[3] = f2bf(eluf(a0.w * i0 + bias[c + 3]));
    *(ushortx4*)(outb + ob + c) = w;
    w[0] = f2bf(eluf(a1.x * i1 + bias[256 + c + 0])); w[1] = f2bf(eluf(a1.y * i1 + bias[256 + c + 1]));
    w[2] = f2bf(eluf(a1.z * i1 + bias[256 + c + 2])); w[3] = f2bf(eluf(a1.w * i1 + bias[256 + c + 3]));
    *(ushortx4*)(outb + ob + 256 + c) = w;
    w[0] = f2bf(eluf(a2.x * i2 + bias[512 + c + 0])); w[1] = f2bf(eluf(a2.y * i2 + bias[512 + c + 1]));
    w[2] = f2bf(eluf(a2.z * i2 + bias[512 + c + 2])); w[3] = f2bf(eluf(a2.w * i2 + bias[512 + c + 3]));
    *(ushortx4*)(outb + ob + 512 + c) = w;
    w[0] = f2bf(eluf(a3.x * i3 + bias[768 + c + 0])); w[1] = f2bf(eluf(a3.y * i3 + bias[768 + c + 1]));
    w[2] = f2bf(eluf(a3.z * i3 + bias[768 + c + 2])); w[3] = f2bf(eluf(a3.w * i3 + bias[768 + c + 3]));
    *(ushortx4*)(outb + ob + 768 + c) = w;
}

// ---------------- layer-2 aggregation (H=1, C=256); bf16 gather -> fp32 out ----------------
__global__ __launch_bounds__(256) void agg2_kernel(const unsigned short* __restrict__ h2b,
        const float* __restrict__ ssrc, const float* __restrict__ sdst,
        const int* __restrict__ row_ptr, const int* __restrict__ col,
        const float* __restrict__ bias, float* __restrict__ out, int N) {
    int wid = (blockIdx.x * blockDim.x + threadIdx.x) >> 6;
    int lane = threadIdx.x & 63;
    if (wid >= N) return;
    int base = row_ptr[wid];
    int deg = row_ptr[wid + 1] - base;
    float sd = sdst[wid];
    float m = -1e30f;
    for (int i = lane; i < deg; i += 64) {
        int s = col[base + i];
        m = fmaxf(m, lrelu(ssrc[s] + sd));
    }
    #pragma unroll
    for (int off = 32; off; off >>= 1) m = fmaxf(m, __shfl_xor(m, off));
    float4 a = {0,0,0,0};
    float den = 0.f;
    int c = lane * 4;
    for (int i = 0; i < deg; i++) {
        int s = col[base + i];
        float x = __expf(lrelu(ssrc[s] + sd) - m); den += x;
        ushortx4 v = *(const ushortx4*)(h2b + (size_t)s * 256 + c);
        a.x += x * bf2f(v[0]); a.y += x * bf2f(v[1]);
        a.z += x * bf2f(v[2]); a.w += x * bf2f(v[3]);
    }
    float inv = 1.f / (den + 1e-16f);
    float4 o;
    o.x = eluf(a.x * inv + bias[c + 0]);
    o.y = eluf(a.y * inv + bias[c + 1]);
    o.z = eluf(a.z * inv + bias[c + 2]);
    o.w = eluf(a.w * inv + bias[c + 3]);
    *(float4*)(out + (size_t)wid * 256 + c) = o;
}

// ---------------- mean over nodes -> graph_features [256] ----------------
__global__ void mean_kernel(const float* __restrict__ h, float* __restrict__ gf, int N) {
    int c = threadIdx.x;
    int per = (N + gridDim.x - 1) / gridDim.x;
    int n0 = blockIdx.x * per;
    int n1 = min(N, n0 + per);
    float acc = 0.f;
    for (int n = n0; n < n1; n++) acc += h[(size_t)n * 256 + c];
    atomicAdd(&gf[c], acc * (1.0f / N));
}

// ---------------- influence head: sigmoid(relu(h@Wp1+bp1)@Wp2+bp2), 4 nodes/block ----------------
__global__ __launch_bounds__(128) void infl_kernel(const float* __restrict__ h,
        const float* __restrict__ Wp1, const float* __restrict__ bp1,
        const float* __restrict__ Wp2, const float* __restrict__ bp2,
        float* __restrict__ infl, int N) {
    __shared__ float sh[4][256];
    __shared__ float red[4][128];
    int nb = blockIdx.x * 4;
    int t = threadIdx.x;
    #pragma unroll
    for (int r = 0; r < 4; r++) {
        int n = nb + r;
        if (n < N) {
            sh[r][t] = h[(size_t)n * 256 + t];
            sh[r][t + 128] = h[(size_t)n * 256 + t + 128];
        }
    }
    __syncthreads();
    float acc0 = bp1[t], acc1 = acc0, acc2 = acc0, acc3 = acc0;
    for (int k = 0; k < 256; k++) {
        float w = Wp1[k * 128 + t];
        acc0 += sh[0][k] * w;
        acc1 += sh[1][k] * w;
        acc2 += sh[2][k] * w;
        acc3 += sh[3][k] * w;
    }
    float w2 = Wp2[t];
    red[0][t] = fmaxf(acc0, 0.f) * w2;
    red[1][t] = fmaxf(acc1, 0.f) * w2;
    red[2][t] = fmaxf(acc2, 0.f) * w2;
    red[3][t] = fmaxf(acc3, 0.f) * w2;
    __syncthreads();
    for (int s = 64; s > 0; s >>= 1) {
        if (t < s) {
            red[0][t] += red[0][t + s];
            red[1][t] += red[1][t + s];
            red[2][t] += red[2][t + s];
            red[3][t] += red[3][t + s];
        }
        __syncthreads();
    }
    if (t < 4) {
        int n = nb + t;
        if (n < N) {
            float v = red[t][0] + bp2[0];
            infl[n] = 1.f / (1.f + __expf(-v));
        }
    }
}

extern "C" void kernel_launch(void* const* d_in, const int* in_sizes, int n_in,
                              void* d_out, int out_size, void* d_ws, size_t ws_size,
                              hipStream_t stream) {
    const float* x   = (const float*)d_in[0];
    const int*   ei  = (const int*)d_in[1];
    const float* W1  = (const float*)d_in[2];
    const float* as1 = (const float*)d_in[3];
    const float* ad1 = (const float*)d_in[4];
    const float* b1  = (const float*)d_in[5];
    const float* W2  = (const float*)d_in[6];
    const float* as2 = (const float*)d_in[7];
    const float* ad2 = (const float*)d_in[8];
    const float* b2  = (const float*)d_in[9];
    const float* Wp1 = (const float*)d_in[10];
    const float* bp1 = (const float*)d_in[11];
    const float* Wp2 = (const float*)d_in[12];
    const float* bp2 = (const float*)d_in[13];

    const int N  = in_sizes[0] / 384;   // 20000
    const int E  = in_sizes[1] / 2;     // 320000
    const int Et = E + N;

    // ---- workspace layout (~95 MB, no aliasing needed) ----
    char* wsp = (char*)d_ws;
    unsigned short* h1b  = (unsigned short*)wsp; wsp += (size_t)N * 1024 * sizeof(short); // GEMM1 out, bf16
    unsigned short* h1eb = (unsigned short*)wsp; wsp += (size_t)N * 1024 * sizeof(short); // agg1 out, bf16
    unsigned short* h2b  = (unsigned short*)wsp; wsp += (size_t)N * 256  * sizeof(short); // GEMM2 out, bf16
    unsigned short* w1th = (unsigned short*)wsp; wsp += (size_t)1024 * 384 * sizeof(short);
    unsigned short* w1tl = (unsigned short*)wsp; wsp += (size_t)1024 * 384 * sizeof(short);
    unsigned short* w2th = (unsigned short*)wsp; wsp += (size_t)256 * 1024 * sizeof(short);
    unsigned short* w2tl = (unsigned short*)wsp; wsp += (size_t)256 * 1024 * sizeof(short);
    float* ss1 = (float*)wsp; wsp += (size_t)N * 4 * sizeof(float);
    float* sd1 = (float*)wsp; wsp += (size_t)N * 4 * sizeof(float);
    float* ss2 = (float*)wsp; wsp += (size_t)N * sizeof(float);
    float* sd2 = (float*)wsp; wsp += (size_t)N * sizeof(float);
    int* row_ptr = (int*)wsp; wsp += (size_t)(N + 1) * sizeof(int);
    int* cursor  = (int*)wsp; wsp += (size_t)N * sizeof(int);
    int* col     = (int*)wsp;

    float* out_h  = (float*)d_out;             // [N,256]
    float* out_gf = out_h + (size_t)N * 256;   // [256]
    float* out_if = out_gf + 256;              // [N]

    // CSR build
    hipMemsetAsync(cursor, 0, (size_t)N * sizeof(int), stream);
    count_kernel<<<(Et + 255) / 256, 256, 0, stream>>>(ei, E, N, cursor);
    scan_kernel<<<1, 1024, 0, stream>>>(cursor, row_ptr, N);
    fill_kernel<<<(Et + 255) / 256, 256, 0, stream>>>(ei, E, N, cursor, col);

    // weight prep (tiny)
    transpose_split<<<dim3(1024 / 32, 384 / 32), dim3(32, 8), 0, stream>>>(W1, w1th, w1tl, 384, 1024);
    transpose_split<<<dim3(256 / 32, 1024 / 32), dim3(32, 8), 0, stream>>>(W2, w2th, w2tl, 1024, 256);

    // layer 1: x (fp32, converted in staging) @ W1 -> h1b bf16
    gemm_2t<true, true, 128><<<dim3(1024 / 128, (N + 127) / 128), 256, 0, stream>>>(
        x, w1th, w1tl, h1b, N, 1024, 384);
    s1_kernel<<<(N + 3) / 4, 256, 0, stream>>>(h1b, as1, ad1, ss1, sd1, N);
    agg1_kernel<<<(N + 3) / 4, 256, 0, stream>>>(h1b, ss1, sd1, row_ptr, col, b1, h1eb, N);

    // layer 2: h1eb bf16 @ W2 -> h2b bf16 (128x64 tiles: 628 blocks for occupancy)
    gemm_2t<false, true, 64><<<dim3(256 / 64, (N + 127) / 128), 256, 0, stream>>>(
        h1eb, w2th, w2tl, h2b, N, 256, 1024);
    s2_kernel<<<(N + 3) / 4, 256, 0, stream>>>(h2b, as2, ad2, ss2, sd2, N);
    agg2_kernel<<<(N + 3) / 4, 256, 0, stream>>>(h2b, ss2, sd2, row_ptr, col, b2, out_h, N);

    // outputs 2 & 3
    hipMemsetAsync(out_gf, 0, 256 * sizeof(float), stream);
    mean_kernel<<<80, 256, 0, stream>>>(out_h, out_gf, N);
    infl_kernel<<<(N + 3) / 4, 128, 0, stream>>>(out_h, Wp1, bp1, Wp2, bp2, out_if, N);
}